// Round 1
// baseline (467.402 us; speedup 1.0000x reference)
//
#include <hip/hip_runtime.h>
#include <hip/hip_bf16.h>

typedef unsigned int uint_t;
typedef __attribute__((ext_vector_type(8))) short bf16x8;   // MFMA A/B frag (4 VGPRs)
typedef __attribute__((ext_vector_type(4))) float f32x4;    // MFMA C/D frag

#define NPTS 50000
#define DIM  64
#define KNB  16
#define GPW  8                  // points per wave (one group per wave)
#define NGROUPS (NPTS / GPW)    // 6250
#define WPB  4                  // waves per block
#define NBLOCKS ((NGROUPS + WPB - 1) / WPB)

// ws layout in 32-bit words: frag images are [f*256 + lane*4 + w]
#define FR_WA    0       // Wa frag image (8 frags)
#define FR_PSIG  2048    // -(Wpsi@Wg) frag image
#define FR_WG    4096    // Wg, rows sigma-permuted, frag image
#define FR_PHIG  6144    // (Wphi@Wg) frag image
#define WC4      8192    // 64 x float4 (wcx,wcy,wcz,wbc)
#define GB       8448    // (bphi-bpsi)@Wg + bg
#define BA       8512    // b_alpha

__device__ __forceinline__ uint_t pk(float a, float b) {
    union { __hip_bfloat162 h; uint_t u; } cv;
    cv.h = __float22bfloat162_rn(float2{a, b});
    return cv.u;
}

union Frag { uint_t u[4]; bf16x8 s; uint4 v; };

// sigma: row-permutation of Wg so that the utr writer's in-lane (nt0,nt1)/(nt2,nt3)
// pairs land as the reader's consecutive A-frag k-dim pairs.
__device__ __forceinline__ int sigma(int k) {
    int t = k >> 1;
    return (t & 15) + 32 * (t >> 4) + 16 * (k & 1);
}

__global__ void pt_prep(const float* __restrict__ Wphi, const float* __restrict__ bphi,
                        const float* __restrict__ Wpsi, const float* __restrict__ bpsi,
                        const float* __restrict__ Wa,   const float* __restrict__ ba,
                        const float* __restrict__ Wg,   const float* __restrict__ bg,
                        const float* __restrict__ Wd1,  const float* __restrict__ bd1,
                        const float* __restrict__ Wd2,  const float* __restrict__ bd2,
                        float* __restrict__ ws) {
    int b = blockIdx.x, t = threadIdx.x;
    uint_t* wsu = (uint_t*)ws;
    if (b < 32) {
        int gid  = b * 256 + t;             // [0, 8192)
        int img  = gid >> 11;               // 0..3
        int rem  = gid & 2047;
        int f    = rem >> 8;                // 0..7  (nt = f>>1, s = f&1)
        int lane = (rem >> 2) & 63;
        int w    = rem & 3;
        int k0   = (f & 1) * 32 + (lane >> 4) * 8 + 2 * w;
        int k1   = k0 + 1;
        int n    = (f >> 1) * 16 + (lane & 15);
        float v0, v1;
        if (img == 0) {                     // Wa
            v0 = Wa[k0 * 64 + n]; v1 = Wa[k1 * 64 + n];
            wsu[FR_WA + rem] = pk(v0, v1);
        } else if (img == 1) {              // -(Wpsi@Wg)
            float a0 = 0.f, a1 = 0.f;
            for (int c = 0; c < 64; ++c) {
                float wgc = Wg[c * 64 + n];
                a0 += Wpsi[k0 * 64 + c] * wgc;
                a1 += Wpsi[k1 * 64 + c] * wgc;
            }
            wsu[FR_PSIG + rem] = pk(-a0, -a1);
        } else if (img == 2) {              // Wg sigma-row-permuted
            v0 = Wg[sigma(k0) * 64 + n]; v1 = Wg[sigma(k1) * 64 + n];
            wsu[FR_WG + rem] = pk(v0, v1);
        } else {                            // Wphi@Wg
            float a0 = 0.f, a1 = 0.f;
            for (int c = 0; c < 64; ++c) {
                float wgc = Wg[c * 64 + n];
                a0 += Wphi[k0 * 64 + c] * wgc;
                a1 += Wphi[k1 * 64 + c] * wgc;
            }
            wsu[FR_PHIG + rem] = pk(a0, a1);
        }
    } else if (t < 64) {
        // wc4: folded W_d1@W_d2 (+ folded bias), gb, ba
        float wx = 0.f, wy = 0.f, wz = 0.f;
        for (int m = 0; m < 64; ++m) {
            float w2 = Wd2[m * 64 + t];
            wx += Wd1[m] * w2;
            wy += Wd1[64 + m] * w2;
            wz += Wd1[128 + m] * w2;
        }
        float wb = bd2[t];
        for (int m = 0; m < 64; ++m) wb += bd1[m] * Wd2[m * 64 + t];
        ws[WC4 + t * 4 + 0] = wx;
        ws[WC4 + t * 4 + 1] = wy;
        ws[WC4 + t * 4 + 2] = wz;
        ws[WC4 + t * 4 + 3] = wb;
        float g = bg[t];
        for (int c = 0; c < 64; ++c) g += (bphi[c] - bpsi[c]) * Wg[c * 64 + t];
        ws[GB + t] = g;
        ws[BA + t] = ba[t];
    }
}

#define MFMA(A, B, C) __builtin_amdgcn_mfma_f32_16x16x32_bf16((A), (B), (C), 0, 0, 0)

// per-wave LDS (words): phig 8*65=520 | utr 16*34=544 | dxyz 2*16*4=128 | pxyz 32
#define WAREA 1224

// Block-shared weight frag images in LDS (wa | wpsig | wg), 1536 uint4 = 24 KB.
// Frees ~96 VGPRs/wave vs register-resident weights -> 3 waves/SIMD occupancy.
__global__ __launch_bounds__(256, 3)
void pt_main(const float* __restrict__ pxyz, const float* __restrict__ pfeat,
             const float* __restrict__ nxyz, const float* __restrict__ nfeat,
             const float* __restrict__ ws,   float* __restrict__ out) {
    __shared__ uint4 wfr[1536];          // [img(3)][f(8)][lane(64)]
    __shared__ float lds[WPB][WAREA];

    const int t    = threadIdx.x;
    const int wv   = t >> 6;
    const int lane = t & 63;
    const int c16  = lane & 15;
    const int quad = lane >> 4;

    const int g = blockIdx.x * WPB + wv;

    // ---- stage block-shared weight frag images (all threads, before any return) ----
    const uint4* fr = (const uint4*)ws;       // frag uint4 index = IMG/4 + f*64 + lane
    #pragma unroll
    for (int idx = 0; idx < 6; ++idx)
        wfr[idx * 256 + t] = fr[idx * 256 + t];
    __syncthreads();

    if (g >= NGROUPS) return;

    float*  phig_s = &lds[wv][0];
    uint_t* utr    = (uint_t*)(phig_s + 520);
    float*  dxyz   = (float*)(utr + 544);
    float*  pxyz_s = dxyz + 128;

    // lane-fixed LDS base for weight frag reads (ds_read_b128 with imm offsets)
    const uint4* wfl = wfr + lane;

    float4 wc[4];
    float ba_r[4], gbr[4];
    #pragma unroll
    for (int nt = 0; nt < 4; ++nt) {
        int d = nt * 16 + c16;
        wc[nt]   = ((const float4*)(ws + WC4))[d];
        ba_r[nt] = ws[BA + d];
        gbr[nt]  = ws[GB + d];
    }

    const int g0 = g * GPW;
    const int k3 = lane / 3, c3 = lane - k3 * 3;   // lane<48: (neighbor, component)

    // ---- preamble ----
    if (lane < 24) pxyz_s[lane] = pxyz[g0 * 3 + lane];
    float nv0 = (lane < 48) ? nxyz[(size_t)g0 * 48 + lane] : 0.f;
    if (lane < 48) dxyz[k3 * 4 + c3] = pxyz_s[c3] - nv0;   // point 0, buf 0

    // phig = pf@(Wphi@Wg) + gb for the 8 points (rows 0..7 of one MFMA pass)
    {
        float4 x0{}, x1{}, x2{}, x3{};
        if (c16 < 8) {
            const float* base = pfeat + (size_t)(g0 + c16) * 64 + quad * 8;
            x0 = *(const float4*)(base);
            x1 = *(const float4*)(base + 4);
            x2 = *(const float4*)(base + 32);
            x3 = *(const float4*)(base + 36);
        }
        Frag pa0, pa1;
        pa0.u[0] = pk(x0.x, x0.y); pa0.u[1] = pk(x0.z, x0.w);
        pa0.u[2] = pk(x1.x, x1.y); pa0.u[3] = pk(x1.z, x1.w);
        pa1.u[0] = pk(x2.x, x2.y); pa1.u[1] = pk(x2.z, x2.w);
        pa1.u[2] = pk(x3.x, x3.y); pa1.u[3] = pk(x3.z, x3.w);
        #pragma unroll
        for (int nt = 0; nt < 4; ++nt) {
            Frag b0, b1;
            b0.v = fr[1536 + (nt * 2 + 0) * 64 + lane];
            b1.v = fr[1536 + (nt * 2 + 1) * 64 + lane];
            f32x4 acc = {gbr[nt], gbr[nt], gbr[nt], gbr[nt]};
            acc = MFMA(pa0.s, b0.s, acc);
            acc = MFMA(pa1.s, b1.s, acc);
            if (quad < 2) {
                #pragma unroll
                for (int r = 0; r < 4; ++r)
                    phig_s[(quad * 4 + r) * 65 + nt * 16 + c16] = acc[r];
            }
        }
    }

    // nf prefetch for point 0; nxyz prefetch for point 1
    const float* nfb = nfeat + (size_t)g0 * (KNB * 64) + (size_t)c16 * 64 + quad * 8;
    float4 f0 = *(const float4*)(nfb);
    float4 f1 = *(const float4*)(nfb + 4);
    float4 f2 = *(const float4*)(nfb + 32);
    float4 f3 = *(const float4*)(nfb + 36);
    float nvn = (lane < 48) ? nxyz[(size_t)g0 * 48 + 48 + lane] : 0.f;

    #pragma unroll 1
    for (int i = 0; i < GPW; ++i) {
        const int n = g0 + i;

        // pack current nf A-frags, then overwrite prefetch regs
        Frag na0, na1;
        na0.u[0] = pk(f0.x, f0.y); na0.u[1] = pk(f0.z, f0.w);
        na0.u[2] = pk(f1.x, f1.y); na0.u[3] = pk(f1.z, f1.w);
        na1.u[0] = pk(f2.x, f2.y); na1.u[1] = pk(f2.z, f2.w);
        na1.u[2] = pk(f3.x, f3.y); na1.u[3] = pk(f3.z, f3.w);
        if (i + 1 < GPW) {
            const float* nf2 = nfb + (size_t)(i + 1) * (KNB * 64);
            f0 = *(const float4*)(nf2);
            f1 = *(const float4*)(nf2 + 4);
            f2 = *(const float4*)(nf2 + 32);
            f3 = *(const float4*)(nf2 + 36);
        }

        // early LDS reads: phig values, this point's dxyz rows
        float ph[4];
        #pragma unroll
        for (int nt = 0; nt < 4; ++nt) ph[nt] = phig_s[i * 65 + nt * 16 + c16];
        float4 dd[4];
        #pragma unroll
        for (int r = 0; r < 4; ++r)
            dd[r] = ((const float4*)dxyz)[(i & 1) * 16 + quad * 4 + r];

        // write next point's dxyz (uses prefetched nvn), then prefetch nxyz i+2
        if (i + 1 < GPW) {
            if (lane < 48)
                dxyz[((i + 1) & 1) * 64 + k3 * 4 + c3] = pxyz_s[(i + 1) * 3 + c3] - nvn;
            if (i + 2 < GPW)
                nvn = (lane < 48) ? nxyz[((size_t)n + 2) * 48 + lane] : 0.f;
        }

        // u = diff@Wc + bc, relu -> delta in C-layout; pack transpose into utr
        float d_c[4][4];
        #pragma unroll
        for (int nt = 0; nt < 4; ++nt) {
            #pragma unroll
            for (int r = 0; r < 4; ++r) {
                float u = fmaf(dd[r].x, wc[nt].x,
                          fmaf(dd[r].y, wc[nt].y,
                          fmaf(dd[r].z, wc[nt].z, wc[nt].w)));
                d_c[nt][r] = fmaxf(u, 0.f);
            }
        }
        #pragma unroll
        for (int r = 0; r < 4; ++r) {
            int row = (quad * 4 + r) * 34;
            utr[row + c16]      = pk(d_c[0][r], d_c[1][r]);
            utr[row + 16 + c16] = pk(d_c[2][r], d_c[3][r]);
        }

        // alpha = nf@Wa + ba (delta added after); overlaps utr write latency
        f32x4 aacc[4];
        #pragma unroll
        for (int nt = 0; nt < 4; ++nt) {
            Frag w0, w1;
            w0.v = wfl[(nt * 2 + 0) * 64];
            w1.v = wfl[(nt * 2 + 1) * 64];
            aacc[nt] = f32x4{ba_r[nt], ba_r[nt], ba_r[nt], ba_r[nt]};
            aacc[nt] = MFMA(na0.s, w0.s, aacc[nt]);
            aacc[nt] = MFMA(na1.s, w1.s, aacc[nt]);
        }
        // gamma = phig - nf@WpsiG ...
        f32x4 gacc[4];
        #pragma unroll
        for (int nt = 0; nt < 4; ++nt) {
            Frag w0, w1;
            w0.v = wfl[512 + (nt * 2 + 0) * 64];
            w1.v = wfl[512 + (nt * 2 + 1) * 64];
            gacc[nt] = f32x4{ph[nt], ph[nt], ph[nt], ph[nt]};
            gacc[nt] = MFMA(na0.s, w0.s, gacc[nt]);
            gacc[nt] = MFMA(na1.s, w1.s, gacc[nt]);
        }
        // ... + delta@Wg (read back transposed delta as ready-made A-frags)
        Frag da0, da1;
        {
            const uint_t* rowp = utr + c16 * 34 + quad * 4;
            uint2 a = *(const uint2*)(rowp);
            uint2 b = *(const uint2*)(rowp + 2);
            uint2 c = *(const uint2*)(rowp + 16);
            uint2 d = *(const uint2*)(rowp + 18);
            da0.u[0] = a.x; da0.u[1] = a.y; da0.u[2] = b.x; da0.u[3] = b.y;
            da1.u[0] = c.x; da1.u[1] = c.y; da1.u[2] = d.x; da1.u[3] = d.y;
        }
        #pragma unroll
        for (int nt = 0; nt < 4; ++nt) {
            Frag w0, w1;
            w0.v = wfl[1024 + (nt * 2 + 0) * 64];
            w1.v = wfl[1024 + (nt * 2 + 1) * 64];
            gacc[nt] = MFMA(da0.s, w0.s, gacc[nt]);
            gacc[nt] = MFMA(da1.s, w1.s, gacc[nt]);
        }
        // alpha finalize
        #pragma unroll
        for (int nt = 0; nt < 4; ++nt)
            #pragma unroll
            for (int r = 0; r < 4; ++r) aacc[nt][r] += d_c[nt][r];

        // softmax over features (no max-sub: |gamma| small by construction)
        float e[4][4], smi[4];
        #pragma unroll
        for (int r = 0; r < 4; ++r) {
            float s = 0.f;
            #pragma unroll
            for (int nt = 0; nt < 4; ++nt) { e[nt][r] = __expf(gacc[nt][r]); s += e[nt][r]; }
            #pragma unroll
            for (int d2 = 1; d2 < 16; d2 <<= 1) s += __shfl_xor(s, d2);
            smi[r] = __builtin_amdgcn_rcpf(s);
        }
        // out_d = sum_k rho*alpha
        float p0 = 0.f, p1 = 0.f, p2 = 0.f, p3 = 0.f;
        #pragma unroll
        for (int r = 0; r < 4; ++r) {
            p0 = fmaf(e[0][r] * smi[r], aacc[0][r], p0);
            p1 = fmaf(e[1][r] * smi[r], aacc[1][r], p1);
            p2 = fmaf(e[2][r] * smi[r], aacc[2][r], p2);
            p3 = fmaf(e[3][r] * smi[r], aacc[3][r], p3);
        }
        p0 += __shfl_xor(p0, 16); p0 += __shfl_xor(p0, 32);
        p1 += __shfl_xor(p1, 16); p1 += __shfl_xor(p1, 32);
        p2 += __shfl_xor(p2, 16); p2 += __shfl_xor(p2, 32);
        p3 += __shfl_xor(p3, 16); p3 += __shfl_xor(p3, 32);
        float sel = (quad == 0) ? p0 : (quad == 1) ? p1 : (quad == 2) ? p2 : p3;
        out[(size_t)n * 64 + lane] = sel;
    }
}

extern "C" void kernel_launch(void* const* d_in, const int* in_sizes, int n_in,
                              void* d_out, int out_size, void* d_ws, size_t ws_size,
                              hipStream_t stream) {
    const float* pxyz  = (const float*)d_in[0];
    const float* pfeat = (const float*)d_in[1];
    const float* nxyz  = (const float*)d_in[2];
    const float* nfeat = (const float*)d_in[3];
    const float* Wphi  = (const float*)d_in[4];
    const float* bphi  = (const float*)d_in[5];
    const float* Wpsi  = (const float*)d_in[6];
    const float* bpsi  = (const float*)d_in[7];
    const float* Wa    = (const float*)d_in[8];
    const float* ba    = (const float*)d_in[9];
    const float* Wg    = (const float*)d_in[10];
    const float* bg    = (const float*)d_in[11];
    const float* Wd1   = (const float*)d_in[12];
    const float* bd1   = (const float*)d_in[13];
    const float* Wd2   = (const float*)d_in[14];
    const float* bd2   = (const float*)d_in[15];
    float* ws = (float*)d_ws;

    pt_prep<<<33, 256, 0, stream>>>(Wphi, bphi, Wpsi, bpsi, Wa, ba, Wg, bg,
                                    Wd1, bd1, Wd2, bd2, ws);
    pt_main<<<NBLOCKS, 256, 0, stream>>>(pxyz, pfeat, nxyz, nfeat, ws, (float*)d_out);
}

// Round 2
// 351.288 us; speedup vs baseline: 1.3305x; 1.3305x over previous
//
#include <hip/hip_runtime.h>
#include <hip/hip_bf16.h>

typedef unsigned int uint_t;
typedef __attribute__((ext_vector_type(8))) short bf16x8;   // MFMA A/B frag (4 VGPRs)
typedef __attribute__((ext_vector_type(4))) float f32x4;    // MFMA C/D frag

#define NPTS 50000
#define DIM  64
#define KNB  16
#define GPW  8                  // points per wave (one group per wave)
#define NGROUPS (NPTS / GPW)    // 6250
#define WPB  4                  // waves per block
#define NBLOCKS ((NGROUPS + WPB - 1) / WPB)

// ws layout in 32-bit words: frag images are [f*256 + lane*4 + w]
#define FR_WA    0       // Wa frag image (8 frags)
#define FR_PSIG  2048    // -(Wpsi@Wg) frag image
#define FR_WG    4096    // Wg, rows sigma-permuted, frag image
#define FR_PHIG  6144    // (Wphi@Wg) frag image
#define WC4      8192    // 64 x float4 (wcx,wcy,wcz,wbc)
#define GB       8448    // (bphi-bpsi)@Wg + bg
#define BA       8512    // b_alpha

__device__ __forceinline__ uint_t pk(float a, float b) {
    union { __hip_bfloat162 h; uint_t u; } cv;
    cv.h = __float22bfloat162_rn(float2{a, b});
    return cv.u;
}

union Frag { uint_t u[4]; bf16x8 s; uint4 v; };

// sigma: row-permutation of Wg so that the utr writer's in-lane (nt0,nt1)/(nt2,nt3)
// pairs land as the reader's consecutive A-frag k-dim pairs.
__device__ __forceinline__ int sigma(int k) {
    int t = k >> 1;
    return (t & 15) + 32 * (t >> 4) + 16 * (k & 1);
}

__global__ void pt_prep(const float* __restrict__ Wphi, const float* __restrict__ bphi,
                        const float* __restrict__ Wpsi, const float* __restrict__ bpsi,
                        const float* __restrict__ Wa,   const float* __restrict__ ba,
                        const float* __restrict__ Wg,   const float* __restrict__ bg,
                        const float* __restrict__ Wd1,  const float* __restrict__ bd1,
                        const float* __restrict__ Wd2,  const float* __restrict__ bd2,
                        float* __restrict__ ws) {
    int b = blockIdx.x, t = threadIdx.x;
    uint_t* wsu = (uint_t*)ws;
    if (b < 32) {
        int gid  = b * 256 + t;             // [0, 8192)
        int img  = gid >> 11;               // 0..3
        int rem  = gid & 2047;
        int f    = rem >> 8;                // 0..7  (nt = f>>1, s = f&1)
        int lane = (rem >> 2) & 63;
        int w    = rem & 3;
        int k0   = (f & 1) * 32 + (lane >> 4) * 8 + 2 * w;
        int k1   = k0 + 1;
        int n    = (f >> 1) * 16 + (lane & 15);
        float v0, v1;
        if (img == 0) {                     // Wa
            v0 = Wa[k0 * 64 + n]; v1 = Wa[k1 * 64 + n];
            wsu[FR_WA + rem] = pk(v0, v1);
        } else if (img == 1) {              // -(Wpsi@Wg)
            float a0 = 0.f, a1 = 0.f;
            for (int c = 0; c < 64; ++c) {
                float wgc = Wg[c * 64 + n];
                a0 += Wpsi[k0 * 64 + c] * wgc;
                a1 += Wpsi[k1 * 64 + c] * wgc;
            }
            wsu[FR_PSIG + rem] = pk(-a0, -a1);
        } else if (img == 2) {              // Wg sigma-row-permuted
            v0 = Wg[sigma(k0) * 64 + n]; v1 = Wg[sigma(k1) * 64 + n];
            wsu[FR_WG + rem] = pk(v0, v1);
        } else {                            // Wphi@Wg
            float a0 = 0.f, a1 = 0.f;
            for (int c = 0; c < 64; ++c) {
                float wgc = Wg[c * 64 + n];
                a0 += Wphi[k0 * 64 + c] * wgc;
                a1 += Wphi[k1 * 64 + c] * wgc;
            }
            wsu[FR_PHIG + rem] = pk(a0, a1);
        }
    } else if (t < 64) {
        // wc4: folded W_d1@W_d2 (+ folded bias), gb, ba
        float wx = 0.f, wy = 0.f, wz = 0.f;
        for (int m = 0; m < 64; ++m) {
            float w2 = Wd2[m * 64 + t];
            wx += Wd1[m] * w2;
            wy += Wd1[64 + m] * w2;
            wz += Wd1[128 + m] * w2;
        }
        float wb = bd2[t];
        for (int m = 0; m < 64; ++m) wb += bd1[m] * Wd2[m * 64 + t];
        ws[WC4 + t * 4 + 0] = wx;
        ws[WC4 + t * 4 + 1] = wy;
        ws[WC4 + t * 4 + 2] = wz;
        ws[WC4 + t * 4 + 3] = wb;
        float g = bg[t];
        for (int c = 0; c < 64; ++c) g += (bphi[c] - bpsi[c]) * Wg[c * 64 + t];
        ws[GB + t] = g;
        ws[BA + t] = ba[t];
    }
}

#define MFMA(A, B, C) __builtin_amdgcn_mfma_f32_16x16x32_bf16((A), (B), (C), 0, 0, 0)

// per-wave LDS word layout:
// phig 520 | utr 544 | dxyz 64 | pxyz 32 | obuf 512 | nf 3*1088 (1024 nfeat + 64 nxyz)
#define O_PHIG 0
#define O_UTR  520
#define O_DXY  1064
#define O_PXY  1128
#define O_OBUF 1160
#define O_NF   1672
#define NFSLOT 1088
#define WAREA  (O_NF + 3 * NFSLOT)   // 4936 words = 19744 B/wave; 78976 B/block (2 blocks/CU)

__device__ __forceinline__ void gl_lds16(const void* g, void* l) {
    __builtin_amdgcn_global_load_lds(
        (const __attribute__((address_space(1))) unsigned int*)g,
        (__attribute__((address_space(3))) unsigned int*)l, 16, 0, 0);
}
__device__ __forceinline__ void gl_lds4(const void* g, void* l) {
    __builtin_amdgcn_global_load_lds(
        (const __attribute__((address_space(1))) unsigned int*)g,
        (__attribute__((address_space(3))) unsigned int*)l, 4, 0, 0);
}

// Stage one point's nfeat (4 KB) + nxyz (192 B) into an LDS slot.
// Source is row-rotated (16B-chunk rotation by neighbor row) so each staging
// instruction's quarter-wave covers one 256B row fully -> full sector merge,
// 1x HBM fetch. LDS dest stays linear (global_load_lds requirement).
__device__ __forceinline__ void stage_pt(const float* __restrict__ nfeat,
                                         const float* __restrict__ nxyz,
                                         int p, float* ldsbase,
                                         const int* soff, int lane) {
    const char* sp = (const char*)nfeat + (size_t)p * 4096;
    gl_lds16(sp + soff[0], ldsbase);
    gl_lds16(sp + soff[1], ldsbase + 256);
    gl_lds16(sp + soff[2], ldsbase + 512);
    gl_lds16(sp + soff[3], ldsbase + 768);
    int xi = p * 48 + lane;
    if (xi > NPTS * KNB * 3 - 1) xi = NPTS * KNB * 3 - 1;   // clamp tail over-read
    gl_lds4(nxyz + xi, ldsbase + 1024);
}

__global__ __launch_bounds__(256, 2)
void pt_main(const float* __restrict__ pxyz, const float* __restrict__ pfeat,
             const float* __restrict__ nxyz, const float* __restrict__ nfeat,
             const float* __restrict__ ws,   float* __restrict__ out) {
    __shared__ float lds[WPB][WAREA];

    const int t    = threadIdx.x;
    const int wv   = t >> 6;
    const int lane = t & 63;
    const int c16  = lane & 15;
    const int quad = lane >> 4;

    const int g = blockIdx.x * WPB + wv;
    if (g >= NGROUPS) return;            // no block-level barriers anywhere

    float*  W      = lds[wv];
    float*  phig_s = W + O_PHIG;
    uint_t* utr    = (uint_t*)(W + O_UTR);
    float*  dxyz   = W + O_DXY;
    float*  pxyz_s = W + O_PXY;
    float*  obuf   = W + O_OBUF;
    float*  nfl    = W + O_NF;

    const int g0 = g * GPW;
    const int k3 = lane / 3, c3 = lane - k3 * 3;   // lane<48: (neighbor, component)

    // per-lane rotated source offsets for the 4 staging instructions
    int soff[4];
    #pragma unroll
    for (int j = 0; j < 4; ++j) {
        int row = j * 4 + quad;                       // neighbor row this lane covers
        soff[j] = row * 256 + (((c16 - row) & 15) << 4);
    }

    // prologue: stage points g0, g0+1 (latency hides under the whole preamble)
    stage_pt(nfeat, nxyz, g0,     nfl + 0 * NFSLOT, soff, lane);
    stage_pt(nfeat, nxyz, g0 + 1, nfl + 1 * NFSLOT, soff, lane);

    // ---- persistent weights in registers (zero-latency MFMA operands) ----
    const uint4* fr = (const uint4*)ws;       // frag uint4 index = IMG/4 + f*64 + lane
    Frag wa[8], wpsig[8], wg[8];
    #pragma unroll
    for (int f = 0; f < 8; ++f) {
        wa[f].v    = fr[        f * 64 + lane];
        wpsig[f].v = fr[ 512 +  f * 64 + lane];
        wg[f].v    = fr[1024 +  f * 64 + lane];
    }
    float4 wc[4];
    float ba_r[4], gbr[4];
    #pragma unroll
    for (int nt = 0; nt < 4; ++nt) {
        int d = nt * 16 + c16;
        wc[nt]   = ((const float4*)(ws + WC4))[d];
        ba_r[nt] = ws[BA + d];
        gbr[nt]  = ws[GB + d];
    }

    if (lane < 24) pxyz_s[lane] = pxyz[g0 * 3 + lane];

    // phig = pf@(Wphi@Wg) + gb for the 8 points (rows 0..7 of one MFMA pass)
    {
        float4 x0{}, x1{}, x2{}, x3{};
        if (c16 < 8) {
            const float* base = pfeat + (size_t)(g0 + c16) * 64 + quad * 8;
            x0 = *(const float4*)(base);
            x1 = *(const float4*)(base + 4);
            x2 = *(const float4*)(base + 32);
            x3 = *(const float4*)(base + 36);
        }
        Frag pa0, pa1;
        pa0.u[0] = pk(x0.x, x0.y); pa0.u[1] = pk(x0.z, x0.w);
        pa0.u[2] = pk(x1.x, x1.y); pa0.u[3] = pk(x1.z, x1.w);
        pa1.u[0] = pk(x2.x, x2.y); pa1.u[1] = pk(x2.z, x2.w);
        pa1.u[2] = pk(x3.x, x3.y); pa1.u[3] = pk(x3.z, x3.w);
        #pragma unroll
        for (int nt = 0; nt < 4; ++nt) {
            Frag b0, b1;
            b0.v = fr[1536 + (nt * 2 + 0) * 64 + lane];
            b1.v = fr[1536 + (nt * 2 + 1) * 64 + lane];
            f32x4 acc = {gbr[nt], gbr[nt], gbr[nt], gbr[nt]};
            acc = MFMA(pa0.s, b0.s, acc);
            acc = MFMA(pa1.s, b1.s, acc);
            if (quad < 2) {
                #pragma unroll
                for (int r = 0; r < 4; ++r)
                    phig_s[(quad * 4 + r) * 65 + nt * 16 + c16] = acc[r];
            }
        }
    }

    int slot = 0;    // LDS slot holding point i
    #pragma unroll 1
    for (int i = 0; i < GPW; ++i) {
        const int n = g0 + i;

        // issue stage for point i+2 (slot (slot+2)%3), then counted wait:
        // keep the 2 in-flight future stages (10 ops) resident across the wait.
        if (i + 2 < GPW) {
            int s2 = slot + 2; if (s2 >= 3) s2 -= 3;
            stage_pt(nfeat, nxyz, n + 2, nfl + s2 * NFSLOT, soff, lane);
        }
        __builtin_amdgcn_sched_barrier(0);
        if (i < GPW - 2)       { asm volatile("s_waitcnt vmcnt(10)" ::: "memory"); }
        else if (i == GPW - 2) { asm volatile("s_waitcnt vmcnt(5)"  ::: "memory"); }
        else                   { asm volatile("s_waitcnt vmcnt(0)"  ::: "memory"); }
        __builtin_amdgcn_sched_barrier(0);

        const float* nfp = nfl + slot * NFSLOT;

        // dxyz for point i from staged nxyz
        if (lane < 48) {
            float v = nfp[1024 + lane];
            dxyz[k3 * 4 + c3] = pxyz_s[i * 3 + c3] - v;
        }

        // nf A-frags from LDS (inverse rotation; 2-way banks = free)
        int b0 = c16 * 64 + (((quad * 2     + c16) & 15) << 2);
        int b1 = c16 * 64 + (((quad * 2 + 1 + c16) & 15) << 2);
        int b2 = c16 * 64 + (((quad * 2 + 8 + c16) & 15) << 2);
        int b3 = c16 * 64 + (((quad * 2 + 9 + c16) & 15) << 2);
        float4 x0 = *(const float4*)(nfp + b0);
        float4 x1 = *(const float4*)(nfp + b1);
        float4 x2 = *(const float4*)(nfp + b2);
        float4 x3 = *(const float4*)(nfp + b3);
        Frag na0, na1;
        na0.u[0] = pk(x0.x, x0.y); na0.u[1] = pk(x0.z, x0.w);
        na0.u[2] = pk(x1.x, x1.y); na0.u[3] = pk(x1.z, x1.w);
        na1.u[0] = pk(x2.x, x2.y); na1.u[1] = pk(x2.z, x2.w);
        na1.u[2] = pk(x3.x, x3.y); na1.u[3] = pk(x3.z, x3.w);

        // phig values for this point
        float ph[4];
        #pragma unroll
        for (int nt = 0; nt < 4; ++nt) ph[nt] = phig_s[i * 65 + nt * 16 + c16];
        // this point's dxyz rows (written above; lgkm-ordered, gap filled by frag reads)
        float4 dd[4];
        #pragma unroll
        for (int r = 0; r < 4; ++r)
            dd[r] = ((const float4*)dxyz)[quad * 4 + r];

        // u = diff@Wc + bc, relu -> delta in C-layout; pack transpose into utr
        float d_c[4][4];
        #pragma unroll
        for (int nt = 0; nt < 4; ++nt) {
            #pragma unroll
            for (int r = 0; r < 4; ++r) {
                float u = fmaf(dd[r].x, wc[nt].x,
                          fmaf(dd[r].y, wc[nt].y,
                          fmaf(dd[r].z, wc[nt].z, wc[nt].w)));
                d_c[nt][r] = fmaxf(u, 0.f);
            }
        }
        #pragma unroll
        for (int r = 0; r < 4; ++r) {
            int row = (quad * 4 + r) * 34;
            utr[row + c16]      = pk(d_c[0][r], d_c[1][r]);
            utr[row + 16 + c16] = pk(d_c[2][r], d_c[3][r]);
        }

        // alpha = nf@Wa + ba (delta added after); overlaps utr write latency
        f32x4 aacc[4];
        #pragma unroll
        for (int nt = 0; nt < 4; ++nt) {
            aacc[nt] = f32x4{ba_r[nt], ba_r[nt], ba_r[nt], ba_r[nt]};
            aacc[nt] = MFMA(na0.s, wa[nt * 2 + 0].s, aacc[nt]);
            aacc[nt] = MFMA(na1.s, wa[nt * 2 + 1].s, aacc[nt]);
        }
        // gamma = phig - nf@WpsiG ...
        f32x4 gacc[4];
        #pragma unroll
        for (int nt = 0; nt < 4; ++nt) {
            gacc[nt] = f32x4{ph[nt], ph[nt], ph[nt], ph[nt]};
            gacc[nt] = MFMA(na0.s, wpsig[nt * 2 + 0].s, gacc[nt]);
            gacc[nt] = MFMA(na1.s, wpsig[nt * 2 + 1].s, gacc[nt]);
        }
        // ... + delta@Wg (read back transposed delta as ready-made A-frags)
        Frag da0, da1;
        {
            const uint_t* rowp = utr + c16 * 34 + quad * 4;
            uint2 a = *(const uint2*)(rowp);
            uint2 b = *(const uint2*)(rowp + 2);
            uint2 c = *(const uint2*)(rowp + 16);
            uint2 d = *(const uint2*)(rowp + 18);
            da0.u[0] = a.x; da0.u[1] = a.y; da0.u[2] = b.x; da0.u[3] = b.y;
            da1.u[0] = c.x; da1.u[1] = c.y; da1.u[2] = d.x; da1.u[3] = d.y;
        }
        #pragma unroll
        for (int nt = 0; nt < 4; ++nt) {
            gacc[nt] = MFMA(da0.s, wg[nt * 2 + 0].s, gacc[nt]);
            gacc[nt] = MFMA(da1.s, wg[nt * 2 + 1].s, gacc[nt]);
        }
        // alpha finalize
        #pragma unroll
        for (int nt = 0; nt < 4; ++nt)
            #pragma unroll
            for (int r = 0; r < 4; ++r) aacc[nt][r] += d_c[nt][r];

        // softmax over features (no max-sub: |gamma| small by construction)
        float e[4][4], smi[4];
        #pragma unroll
        for (int r = 0; r < 4; ++r) {
            float s = 0.f;
            #pragma unroll
            for (int nt = 0; nt < 4; ++nt) { e[nt][r] = __expf(gacc[nt][r]); s += e[nt][r]; }
            #pragma unroll
            for (int d2 = 1; d2 < 16; d2 <<= 1) s += __shfl_xor(s, d2);
            smi[r] = __builtin_amdgcn_rcpf(s);
        }
        // out_d = sum_k rho*alpha
        float p0 = 0.f, p1 = 0.f, p2 = 0.f, p3 = 0.f;
        #pragma unroll
        for (int r = 0; r < 4; ++r) {
            p0 = fmaf(e[0][r] * smi[r], aacc[0][r], p0);
            p1 = fmaf(e[1][r] * smi[r], aacc[1][r], p1);
            p2 = fmaf(e[2][r] * smi[r], aacc[2][r], p2);
            p3 = fmaf(e[3][r] * smi[r], aacc[3][r], p3);
        }
        p0 += __shfl_xor(p0, 16); p0 += __shfl_xor(p0, 32);
        p1 += __shfl_xor(p1, 16); p1 += __shfl_xor(p1, 32);
        p2 += __shfl_xor(p2, 16); p2 += __shfl_xor(p2, 32);
        p3 += __shfl_xor(p3, 16); p3 += __shfl_xor(p3, 32);
        float sel = (quad == 0) ? p0 : (quad == 1) ? p1 : (quad == 2) ? p2 : p3;
        obuf[i * 64 + lane] = sel;                 // buffer; wide store after loop

        slot = (slot == 2) ? 0 : slot + 1;
    }

    // one contiguous 2 KB store per wave (dwordx4 -> true-size write counting)
    float4 o0 = ((const float4*)obuf)[lane * 2];
    float4 o1 = ((const float4*)obuf)[lane * 2 + 1];
    float4* og = (float4*)(out + (size_t)g0 * 64);
    og[lane * 2]     = o0;
    og[lane * 2 + 1] = o1;
}

extern "C" void kernel_launch(void* const* d_in, const int* in_sizes, int n_in,
                              void* d_out, int out_size, void* d_ws, size_t ws_size,
                              hipStream_t stream) {
    const float* pxyz  = (const float*)d_in[0];
    const float* pfeat = (const float*)d_in[1];
    const float* nxyz  = (const float*)d_in[2];
    const float* nfeat = (const float*)d_in[3];
    const float* Wphi  = (const float*)d_in[4];
    const float* bphi  = (const float*)d_in[5];
    const float* Wpsi  = (const float*)d_in[6];
    const float* bpsi  = (const float*)d_in[7];
    const float* Wa    = (const float*)d_in[8];
    const float* ba    = (const float*)d_in[9];
    const float* Wg    = (const float*)d_in[10];
    const float* bg    = (const float*)d_in[11];
    const float* Wd1   = (const float*)d_in[12];
    const float* bd1   = (const float*)d_in[13];
    const float* Wd2   = (const float*)d_in[14];
    const float* bd2   = (const float*)d_in[15];
    float* ws = (float*)d_ws;

    pt_prep<<<33, 256, 0, stream>>>(Wphi, bphi, Wpsi, bpsi, Wa, ba, Wg, bg,
                                    Wd1, bd1, Wd2, bd2, ws);
    pt_main<<<NBLOCKS, 256, 0, stream>>>(pxyz, pfeat, nxyz, nfeat, ws, (float*)d_out);
}